// Round 1
// baseline (996.695 us; speedup 1.0000x reference)
//
#include <hip/hip_runtime.h>

#define NBATCH 64
#define NHEADS 32
#define HDIM   128
#define NKVH   8
#define GQ     4      // query heads per kv head
#define BLKSZ  16
#define MAXBLK 128
#define SCALE  0.08838834764831845f

// One workgroup per (batch, kv_head). 256 threads = 4 waves.
// Each wave processes 2 tokens per iteration: lanes 0-31 -> token A,
// lanes 32-63 -> token B; each lane holds 4 dims (float4).
__global__ __launch_bounds__(256, 2) void pa_decode(
    const float* __restrict__ q,
    const float* __restrict__ kc,
    const float* __restrict__ vc,
    const int*   __restrict__ block_tables,
    const int*   __restrict__ context_lens,
    float*       __restrict__ out)
{
    const int kvh  = blockIdx.x;
    const int b    = blockIdx.y;
    const int tid  = threadIdx.x;
    const int wave = tid >> 6;      // 0..3
    const int lane = tid & 63;
    const int half = lane >> 5;     // token-within-pair
    const int l32  = lane & 31;     // lane within half

    __shared__ int   s_bt[MAXBLK];
    __shared__ float s_m[4][GQ];
    __shared__ float s_l[4][GQ];
    __shared__ float s_acc[4][GQ][HDIM];   // 8 KB

    const int L = context_lens[b];
    if (tid < MAXBLK) s_bt[tid] = block_tables[b * MAXBLK + tid];
    __syncthreads();

    // q fragments for the 4 query heads, pre-scaled by 1/sqrt(D)
    float4 qv[GQ];
#pragma unroll
    for (int g = 0; g < GQ; ++g) {
        const float4 t = *(const float4*)(q + ((b * NHEADS + kvh * GQ + g) << 7) + 4 * l32);
        qv[g] = make_float4(t.x * SCALE, t.y * SCALE, t.z * SCALE, t.w * SCALE);
    }

    float  m[GQ], l[GQ];
    float4 acc[GQ];
#pragma unroll
    for (int g = 0; g < GQ; ++g) {
        m[g] = -__builtin_inff();
        l[g] = 0.f;
        acc[g] = make_float4(0.f, 0.f, 0.f, 0.f);
    }

    // address of this lane's float4 within token t's K/V vector for our kvh
    auto addr = [&](int t) -> int {
        const int blk = s_bt[t >> 4];
        return ((blk * BLKSZ + (t & 15)) * NKVH + kvh) * HDIM + 4 * l32;
    };

    const int tfirst = wave * 2 + half;
    float4 kcur, vcur;
    kcur = make_float4(0.f, 0.f, 0.f, 0.f);
    vcur = kcur;
    if (wave * 2 < L) {   // this wave has at least one iteration
        const int tt = (tfirst < L) ? tfirst : 0;
        const int o = addr(tt);
        kcur = *(const float4*)(kc + o);
        vcur = *(const float4*)(vc + o);
    }

    for (int base = 0; base + wave * 2 < L; base += 8) {
        const int  t     = base + wave * 2 + half;
        const bool valid = t < L;

        // prefetch next pair (clamped to token 0 when past the end; value unused)
        const int tn  = t + 8;
        const int ttn = (tn < L) ? tn : 0;
        const int on  = addr(ttn);
        const float4 knxt = *(const float4*)(kc + on);
        const float4 vnxt = *(const float4*)(vc + on);

        // per-lane dot partials (4 dims) for 4 heads
        float s[GQ];
#pragma unroll
        for (int g = 0; g < GQ; ++g)
            s[g] = qv[g].x * kcur.x + qv[g].y * kcur.y + qv[g].z * kcur.z + qv[g].w * kcur.w;

        // reduce across the 32 lanes of each half
#pragma unroll
        for (int d2 = 1; d2 < 32; d2 <<= 1) {
#pragma unroll
            for (int g = 0; g < GQ; ++g)
                s[g] += __shfl_xor(s[g], d2);
        }
        if (!valid) {
#pragma unroll
            for (int g = 0; g < GQ; ++g) s[g] = -__builtin_inff();
        }

        // online softmax update; m is wave-uniform (both halves see both scores)
#pragma unroll
        for (int g = 0; g < GQ; ++g) {
            const float so    = __shfl_xor(s[g], 32);
            const float mnew  = fmaxf(m[g], fmaxf(s[g], so));
            const float p     = __expf(s[g] - mnew);   // own token's weight (0 if masked)
            const float alpha = __expf(m[g] - mnew);   // 0 on first iteration (m=-inf)
            m[g] = mnew;
            l[g] = l[g] * alpha + p;
            acc[g].x = acc[g].x * alpha + p * vcur.x;
            acc[g].y = acc[g].y * alpha + p * vcur.y;
            acc[g].z = acc[g].z * alpha + p * vcur.z;
            acc[g].w = acc[g].w * alpha + p * vcur.w;
        }
        kcur = knxt;
        vcur = vnxt;
    }

    // merge the two halves of each wave (shared m, so plain sums)
#pragma unroll
    for (int g = 0; g < GQ; ++g) {
        l[g]     += __shfl_xor(l[g], 32);
        acc[g].x += __shfl_xor(acc[g].x, 32);
        acc[g].y += __shfl_xor(acc[g].y, 32);
        acc[g].z += __shfl_xor(acc[g].z, 32);
        acc[g].w += __shfl_xor(acc[g].w, 32);
    }

    if (lane == 0) {
#pragma unroll
        for (int g = 0; g < GQ; ++g) { s_m[wave][g] = m[g]; s_l[wave][g] = l[g]; }
    }
    if (half == 0) {
#pragma unroll
        for (int g = 0; g < GQ; ++g)
            *(float4*)&s_acc[wave][g][4 * l32] = acc[g];
    }
    __syncthreads();

    // cross-wave flash-decode combine; 512 outputs over 256 threads
    for (int o = tid; o < GQ * HDIM; o += 256) {
        const int g = o >> 7;
        const int d = o & 127;
        const float mg = fmaxf(fmaxf(s_m[0][g], s_m[1][g]), fmaxf(s_m[2][g], s_m[3][g]));
        float num = 0.f, den = 0.f;
#pragma unroll
        for (int w = 0; w < 4; ++w) {
            const float sc = __expf(s_m[w][g] - mg);   // 0 for idle waves (m=-inf)
            num += sc * s_acc[w][g][d];
            den += sc * s_l[w][g];
        }
        out[((b * NHEADS + kvh * GQ + g) << 7) + d] = num / den;
    }
}

extern "C" void kernel_launch(void* const* d_in, const int* in_sizes, int n_in,
                              void* d_out, int out_size, void* d_ws, size_t ws_size,
                              hipStream_t stream) {
    const float* q   = (const float*)d_in[0];
    const float* kc  = (const float*)d_in[1];
    const float* vc  = (const float*)d_in[2];
    const int*   bt  = (const int*)d_in[3];
    const int*   ctx = (const int*)d_in[4];
    float* out = (float*)d_out;

    dim3 grid(NKVH, NBATCH);   // 512 workgroups
    pa_decode<<<grid, 256, 0, stream>>>(q, kc, vc, bt, ctx, out);
}

// Round 2
// 891.433 us; speedup vs baseline: 1.1181x; 1.1181x over previous
//
#include <hip/hip_runtime.h>

#define NBATCH 64
#define NHEADS 32
#define HDIM   128
#define NKVH   8
#define GQ     4      // query heads per kv head
#define BLKSZ  16
#define MAXBLK 128
#define SCALE  0.08838834764831845f

#define CHUNK  128                 // tokens per partition
#define NPARTS 16                  // MAXBLK*BLKSZ / CHUNK
#define PART_STRIDE (GQ*HDIM + 2*GQ)   // acc[4][128], m[4], l[4]

// ---------------- Kernel 1: per-(b,kvh,chunk) partial attention ----------------
// 256 threads = 4 waves. Each wave handles 4 tokens/iter: lanes 0-31 -> tokens
// {t, t+1}, lanes 32-63 -> {t+2, t+3}; each lane holds 4 dims (float4).
__global__ __launch_bounds__(256, 4) void pa_partial(
    const float* __restrict__ q,
    const float* __restrict__ kc,
    const float* __restrict__ vc,
    const int*   __restrict__ block_tables,
    const int*   __restrict__ context_lens,
    float*       __restrict__ part)
{
    const int kvh = blockIdx.x;
    const int b   = blockIdx.y;
    const int p   = blockIdx.z;
    const int L   = context_lens[b];
    const int start = p * CHUNK;
    if (start >= L) return;                    // uniform exit
    const int end = min(L, start + CHUNK);

    const int tid  = threadIdx.x;
    const int wave = tid >> 6;
    const int lane = tid & 63;
    const int half = lane >> 5;
    const int l32  = lane & 31;

    __shared__ int   s_bt[CHUNK / BLKSZ];      // 8 page ids
    __shared__ float s_m[4][GQ];
    __shared__ float s_l[4][GQ];
    __shared__ float s_acc[4][GQ][HDIM];       // 8 KB

    const int nblk = (end - start + BLKSZ - 1) / BLKSZ;
    if (tid < nblk) s_bt[tid] = block_tables[b * MAXBLK + (start >> 4) + tid];
    __syncthreads();

    float4 qv[GQ];
#pragma unroll
    for (int g = 0; g < GQ; ++g) {
        const float4 t = *(const float4*)(q + ((b * NHEADS + kvh * GQ + g) << 7) + 4 * l32);
        qv[g] = make_float4(t.x * SCALE, t.y * SCALE, t.z * SCALE, t.w * SCALE);
    }

    float  m[GQ], l[GQ];
    float4 acc[GQ];
#pragma unroll
    for (int g = 0; g < GQ; ++g) {
        m[g] = -__builtin_inff();
        l[g] = 0.f;
        acc[g] = make_float4(0.f, 0.f, 0.f, 0.f);
    }

    auto addr = [&](int t) -> int {            // t in [start, end)
        const int blk = s_bt[(t - start) >> 4];
        return ((blk * BLKSZ + (t & 15)) * NKVH + kvh) * HDIM + 4 * l32;
    };
    auto clampt = [&](int t) -> int { return t < end ? t : start; };

    const int wbase = start + wave * 4;
    float4 k0, k1, v0, v1;
    if (wbase < end) {
        const int a0 = addr(clampt(wbase + half * 2));
        const int a1 = addr(clampt(wbase + half * 2 + 1));
        k0 = *(const float4*)(kc + a0);
        k1 = *(const float4*)(kc + a1);
        v0 = *(const float4*)(vc + a0);
        v1 = *(const float4*)(vc + a1);
    }

    for (int tb = wbase; tb < end; tb += 16) {
        const int t0 = tb + half * 2;
        const int t1 = t0 + 1;

        // prefetch next iteration (wave-uniform guard)
        float4 nk0, nk1, nv0, nv1;
        const int nb = tb + 16;
        if (nb < end) {
            const int a0 = addr(clampt(nb + half * 2));
            const int a1 = addr(clampt(nb + half * 2 + 1));
            nk0 = *(const float4*)(kc + a0);
            nk1 = *(const float4*)(kc + a1);
            nv0 = *(const float4*)(vc + a0);
            nv1 = *(const float4*)(vc + a1);
        }

        // per-lane dot partials for 2 tokens x 4 heads
        float s0[GQ], s1[GQ];
#pragma unroll
        for (int g = 0; g < GQ; ++g) {
            s0[g] = qv[g].x * k0.x + qv[g].y * k0.y + qv[g].z * k0.z + qv[g].w * k0.w;
            s1[g] = qv[g].x * k1.x + qv[g].y * k1.y + qv[g].z * k1.z + qv[g].w * k1.w;
        }
        // butterfly across the 32 lanes of each half (8 independent values/step)
#pragma unroll
        for (int d2 = 1; d2 < 32; d2 <<= 1) {
#pragma unroll
            for (int g = 0; g < GQ; ++g) {
                s0[g] += __shfl_xor(s0[g], d2);
                s1[g] += __shfl_xor(s1[g], d2);
            }
        }
        if (t0 >= end) {
#pragma unroll
            for (int g = 0; g < GQ; ++g) s0[g] = -__builtin_inff();
        }
        if (t1 >= end) {
#pragma unroll
            for (int g = 0; g < GQ; ++g) s1[g] = -__builtin_inff();
        }

        // online softmax; m wave-uniform via cross-half exchange
#pragma unroll
        for (int g = 0; g < GQ; ++g) {
            const float o0 = __shfl_xor(s0[g], 32);
            const float o1 = __shfl_xor(s1[g], 32);
            const float mnew = fmaxf(m[g], fmaxf(fmaxf(s0[g], s1[g]), fmaxf(o0, o1)));
            const float al = __expf(m[g] - mnew);
            const float p0 = __expf(s0[g] - mnew);
            const float p1 = __expf(s1[g] - mnew);
            m[g] = mnew;
            l[g] = l[g] * al + p0 + p1;
            acc[g].x = acc[g].x * al + p0 * v0.x + p1 * v1.x;
            acc[g].y = acc[g].y * al + p0 * v0.y + p1 * v1.y;
            acc[g].z = acc[g].z * al + p0 * v0.z + p1 * v1.z;
            acc[g].w = acc[g].w * al + p0 * v0.w + p1 * v1.w;
        }
        k0 = nk0; k1 = nk1; v0 = nv0; v1 = nv1;
    }

    // merge the two halves (shared m -> plain sums)
#pragma unroll
    for (int g = 0; g < GQ; ++g) {
        l[g]     += __shfl_xor(l[g], 32);
        acc[g].x += __shfl_xor(acc[g].x, 32);
        acc[g].y += __shfl_xor(acc[g].y, 32);
        acc[g].z += __shfl_xor(acc[g].z, 32);
        acc[g].w += __shfl_xor(acc[g].w, 32);
    }

    if (lane == 0) {
#pragma unroll
        for (int g = 0; g < GQ; ++g) { s_m[wave][g] = m[g]; s_l[wave][g] = l[g]; }
    }
    if (half == 0) {
#pragma unroll
        for (int g = 0; g < GQ; ++g)
            *(float4*)&s_acc[wave][g][4 * l32] = acc[g];
    }
    __syncthreads();

    // cross-wave combine -> unnormalized partial (acc under mg, plus mg, den)
    float* pp = part + (size_t)((b * NKVH + kvh) * NPARTS + p) * PART_STRIDE;
    for (int o = tid; o < GQ * HDIM; o += 256) {
        const int g = o >> 7;
        const int d = o & 127;
        const float mg = fmaxf(fmaxf(s_m[0][g], s_m[1][g]), fmaxf(s_m[2][g], s_m[3][g]));
        float num = 0.f, den = 0.f;
#pragma unroll
        for (int w = 0; w < 4; ++w) {
            const float sc = __expf(s_m[w][g] - mg);   // 0 for idle waves
            num += sc * s_acc[w][g][d];
            den += sc * s_l[w][g];
        }
        pp[g * HDIM + d] = num;
        if (d == 0) {
            pp[GQ * HDIM + g]      = mg;
            pp[GQ * HDIM + GQ + g] = den;
        }
    }
}

// ---------------- Kernel 2: combine partials per (b,kvh) ----------------
__global__ __launch_bounds__(256) void pa_reduce(
    const float* __restrict__ part,
    const int*   __restrict__ context_lens,
    float*       __restrict__ out)
{
    const int kvh = blockIdx.x;
    const int b   = blockIdx.y;
    const int L   = context_lens[b];
    const int np  = (L + CHUNK - 1) / CHUNK;   // 1..16 active partitions
    const float* pb = part + (size_t)(b * NKVH + kvh) * NPARTS * PART_STRIDE;
    const int tid = threadIdx.x;

    __shared__ float sm[NPARTS][GQ];
    __shared__ float sl[NPARTS][GQ];
    if (tid < NPARTS * GQ) {
        const int pi = tid >> 2, g = tid & 3;
        if (pi < np) {
            sm[pi][g] = pb[pi * PART_STRIDE + GQ * HDIM + g];
            sl[pi][g] = pb[pi * PART_STRIDE + GQ * HDIM + GQ + g];
        }
    }
    __syncthreads();

    for (int o = tid; o < GQ * HDIM; o += 256) {
        const int g = o >> 7;
        const int d = o & 127;
        float mg = -__builtin_inff();
        for (int pi = 0; pi < np; ++pi) mg = fmaxf(mg, sm[pi][g]);
        float num = 0.f, den = 0.f;
        for (int pi = 0; pi < np; ++pi) {
            const float sc = __expf(sm[pi][g] - mg);
            num += sc * pb[pi * PART_STRIDE + g * HDIM + d];
            den += sc * sl[pi][g];
        }
        out[((b * NHEADS + kvh * GQ + g) << 7) + d] = num / den;
    }
}

extern "C" void kernel_launch(void* const* d_in, const int* in_sizes, int n_in,
                              void* d_out, int out_size, void* d_ws, size_t ws_size,
                              hipStream_t stream) {
    const float* q   = (const float*)d_in[0];
    const float* kc  = (const float*)d_in[1];
    const float* vc  = (const float*)d_in[2];
    const int*   bt  = (const int*)d_in[3];
    const int*   ctx = (const int*)d_in[4];
    float* out  = (float*)d_out;
    float* part = (float*)d_ws;   // 16 * 512 * 520 * 4B ~= 17 MB << ws_size

    dim3 grid1(NKVH, NBATCH, NPARTS);   // 8192 WGs, ~4100 active
    pa_partial<<<grid1, 256, 0, stream>>>(q, kc, vc, bt, ctx, part);

    dim3 grid2(NKVH, NBATCH);
    pa_reduce<<<grid2, 256, 0, stream>>>(part, ctx, out);
}